// Round 13
// baseline (241.903 us; speedup 1.0000x reference)
//
#include <hip/hip_runtime.h>
#include <hip/hip_bf16.h>

// ---------------------------------------------------------------------------
// qr_k: per (b,h): X0row = emb[tok[b,0]] + PE_row0 (sin0=0 even d, cos0=1 odd)
//   q0[f] = X0row . Wq[h][:,f] + bq[f];  alpha[b,h] = q0 . bk[h]
//   r[(b*4+h)][d] = sum_f q0[f] * Wk[h][d][f]
// Grid (32 b, 4 h).  Block (0,0) zeroes the 128-dword counter block (Acc,
// Cnt, cntA, cntCD) used by the fused kernels' spin gates.
// ---------------------------------------------------------------------------
__global__ __launch_bounds__(256) void qr_k(
    const int* __restrict__ inp, const float* __restrict__ emb,
    const float* __restrict__ Wp, const float* __restrict__ bp,
    float* __restrict__ X0, float* __restrict__ r, float* __restrict__ alpha,
    int* __restrict__ zbase)
{
    __shared__ float xs[512];
    __shared__ float red[256];
    __shared__ float q0s[128];
    int b = blockIdx.x, h = blockIdx.y, t = threadIdx.x;
    if (b == 0 && h == 0 && t < 128) zbase[t] = 0;
    int tok0 = inp[b * 1024];
#pragma unroll
    for (int rep = 0; rep < 2; rep++) {
        int d = t + rep * 256;
        float v = emb[(long)tok0 * 512 + d] + ((d & 1) ? 1.0f : 0.0f);
        xs[d] = v;
        if (h == 0) X0[b * 512 + d] = v;
    }
    __syncthreads();

    int f = t & 127, dh = t >> 7;
    const float* wq = Wp + (long)h * 196608 + f;
    float acc = 0.f;
#pragma unroll 8
    for (int d = dh * 256; d < dh * 256 + 256; d++)
        acc += xs[d] * wq[(long)d * 384];
    red[t] = acc;
    __syncthreads();
    if (t < 128) q0s[t] = red[t] + red[t + 128] + bp[h * 384 + t];
    __syncthreads();
    if (t < 128) red[t] = q0s[t] * bp[h * 384 + 128 + t];
    __syncthreads();
    for (int w = 64; w >= 1; w >>= 1) {
        if (t < w) red[t] += red[t + w];
        __syncthreads();
    }
    if (t == 0) alpha[b * 4 + h] = red[0];

    const float4* q4 = (const float4*)q0s;
#pragma unroll
    for (int rep = 0; rep < 2; rep++) {
        int d = t + rep * 256;
        const float4* wr = (const float4*)(Wp + ((long)(h * 512 + d)) * 384 + 128);
        float a2 = 0.f;
#pragma unroll 8
        for (int f4 = 0; f4 < 32; f4++) {
            float4 w = wr[f4], qq = q4[f4];
            a2 += w.x * qq.x + w.y * qq.y + w.z * qq.z + w.w * qq.w;
        }
        r[((long)(b * 4 + h)) * 512 + d] = a2;
    }
}

// ---------------------------------------------------------------------------
// xu_k: fused x-gather (PE via native __sinf/__cosf) -> u -> t' partials.
// Grid (32 b, 16 sg), 2 chunks of 32 s per block. rs stride 520 (no conflicts).
// ---------------------------------------------------------------------------
__global__ __launch_bounds__(256) void xu_k(
    const int* __restrict__ inp, const float* __restrict__ emb,
    const float* __restrict__ r, const float* __restrict__ alpha,
    float* __restrict__ Tpp, float* __restrict__ Gp)
{
    __shared__ float xs[32 * 516];     // 66 KB
    __shared__ float rs[4 * 520];
    __shared__ float us[128];
    __shared__ int  toks[32];
    int b = blockIdx.x, sg = blockIdx.y, t = threadIdx.x;
    int wave = t >> 6, lane = t & 63;

#pragma unroll
    for (int i = 0; i < 2; i++) {
        int idx = t + i * 256;
        int h = idx >> 7, k4 = idx & 127;
        *(float4*)&rs[h * 520 + k4 * 4] =
            *(const float4*)&r[((long)(b * 4 + h)) * 512 + k4 * 4];
    }

    float w4[4];
#pragma unroll
    for (int j = 0; j < 4; j++) {
        float expo = (float)(lane * 8 + j * 2) * (1.0f / 512.0f);
        w4[j] = exp2f(-expo * 13.287712379549449f);   // 10000^-expo
    }

    float accT[4][2] = {};
    float gacc = 0.f;
    for (int it = 0; it < 2; it++) {
        int s0 = (sg * 2 + it) * 32;
        __syncthreads();
        if (t < 32) toks[t] = inp[b * 1024 + s0 + t];
        __syncthreads();

#pragma unroll
        for (int i = 0; i < 8; i++) {
            int row = wave * 8 + i;
            float s = (float)(s0 + row);
            int tok = toks[row];
            const float4* e = (const float4*)&emb[(long)tok * 512 + lane * 8];
            float4 e0 = e[0], e1 = e[1];
            float sv[4], cv[4];
#pragma unroll
            for (int j = 0; j < 4; j++) {
                float ang = s * w4[j];
                sv[j] = __sinf(ang);
                cv[j] = __cosf(ang);
            }
            *(float4*)&xs[row * 516 + lane * 8] =
                make_float4(e0.x + sv[0], e0.y + cv[0], e0.z + sv[1], e0.w + cv[1]);
            *(float4*)&xs[row * 516 + lane * 8 + 4] =
                make_float4(e1.x + sv[2], e1.y + cv[2], e1.z + sv[3], e1.w + cv[3]);
        }
        __syncthreads();

        {
            int s = t >> 3, h = (t >> 1) & 3, half = t & 1;
            const float* xrow = xs + s * 516 + half * 256;
            const float* rrow = rs + h * 520 + half * 256;
            float acc = 0.f;
#pragma unroll 8
            for (int k = 0; k < 64; k++) {
                float4 xv = *(const float4*)&xrow[k * 4];
                float4 rv = *(const float4*)&rrow[k * 4];
                acc += xv.x * rv.x + xv.y * rv.y + xv.z * rv.z + xv.w * rv.w;
            }
            acc += __shfl_xor(acc, 1);
            if (half == 0) us[s * 4 + h] = acc + alpha[b * 4 + h];
        }
        __syncthreads();

        if (t < 4) {
#pragma unroll
            for (int s = 0; s < 32; s++) gacc += us[s * 4 + t];
        }

#pragma unroll 4
        for (int s = 0; s < 32; s++) {
            float x0 = xs[s * 516 + t];
            float x1 = xs[s * 516 + 256 + t];
#pragma unroll
            for (int h = 0; h < 4; h++) {
                float uv = us[s * 4 + h];
                accT[h][0] += uv * x0;
                accT[h][1] += uv * x1;
            }
        }
    }
    long base = (long)(b * 16 + sg) * 2048;
#pragma unroll
    for (int h = 0; h < 4; h++) {
        Tpp[base + h * 512 + t] = accT[h][0];
        Tpp[base + h * 512 + 256 + t] = accT[h][1];
    }
    if (t < 4) Gp[(b * 16 + sg) * 4 + t] = gacc;
}

// ---------------------------------------------------------------------------
// attf_k: fused att1 + att2s via per-b spin gate.  Grid (32 b, 16 roles).
//   role<8  (att1): c0 slice = scale*(t'.Wv + gamma*bv); signal cntA[b].
//   role>=8 (att2s): wait cntA[b]==8; A1 = C0@Wo + bo + X0; LN stats.
// All 512 blocks co-resident (small LDS) -> gates cannot deadlock.
// ---------------------------------------------------------------------------
__global__ __launch_bounds__(256) void attf_k(
    const float* __restrict__ Tpp, const float* __restrict__ Gp,
    const float* __restrict__ Wp, const float* __restrict__ bp,
    const float* __restrict__ Wo, const float* __restrict__ bo,
    const float* __restrict__ X0, float* __restrict__ C0,
    float* __restrict__ A1, float* __restrict__ Stat, int* __restrict__ cntA)
{
    __shared__ float tps[512];
    __shared__ float red[256];
    int b = blockIdx.x, role = blockIdx.y, t = threadIdx.x;

    if (role < 8) {
        int jt = role;
        int h = jt >> 1, e0 = (jt & 1) * 64;
#pragma unroll
        for (int i = 0; i < 2; i++) {
            int d = t + i * 256;
            float v = 0.f;
#pragma unroll 8
            for (int sg = 0; sg < 16; sg++)
                v += Tpp[(long)b * 32768 + sg * 2048 + h * 512 + d];
            tps[d] = v;
        }
        __syncthreads();
        int e = e0 + (t & 63), rg = t >> 6;
        const float* wv = Wp + (long)h * 196608 + 256 + e;
        float acc = 0.f;
#pragma unroll 8
        for (int d = rg * 128; d < rg * 128 + 128; d++)
            acc += tps[d] * wv[(long)d * 384];
        red[t] = acc;
        __syncthreads();
        if (t < 64) {
            float gam = 0.f;
#pragma unroll
            for (int sg = 0; sg < 16; sg++) gam += Gp[(b * 16 + sg) * 4 + h];
            float sum = red[t] + red[t + 64] + red[t + 128] + red[t + 192];
            float c = 0.03125f * (sum + gam * bp[h * 384 + 256 + e0 + t]);
            C0[b * 512 + h * 128 + e0 + t] = c;
        }
        __syncthreads();
        if (t == 0) {
            __threadfence();
            atomicAdd(&cntA[b], 1);
        }
    } else {
        int jt = role - 8;
        if (t == 0) {
            while (atomicAdd(&cntA[b], 0) < 8) __builtin_amdgcn_s_sleep(2);
            __threadfence();
        }
        __syncthreads();
        float* c0s = tps;
        c0s[t] = C0[b * 512 + t];
        c0s[t + 256] = C0[b * 512 + t + 256];
        __syncthreads();
        int j = jt * 64 + (t & 63), rg = t >> 6;
        float acc = 0.f;
#pragma unroll 8
        for (int d = rg * 128; d < rg * 128 + 128; d++)
            acc += c0s[d] * Wo[(long)d * 512 + j];
        red[t] = acc;
        __syncthreads();
        if (t < 64) {
            int jj = jt * 64 + t;
            float a = red[t] + red[t + 64] + red[t + 128] + red[t + 192]
                    + bo[jj] + X0[b * 512 + jj];
            A1[b * 512 + jj] = a;
            float s = a, q = a * a;
#pragma unroll
            for (int off = 32; off; off >>= 1) {
                s += __shfl_down(s, off);
                q += __shfl_down(q, off);
            }
            if (t == 0) {
                Stat[(b * 8 + jt) * 2]     = s;
                Stat[(b * 8 + jt) * 2 + 1] = q;
            }
        }
    }
}

// ---------------------------------------------------------------------------
// fh_k: fused ffn1 + ffn2 + headp3 via global spin gates.  Grid 512 flat:
//   z<128: ffn1 (LN1-on-load); signal cntCD[0].
//   z<256: ffn2 (wait cntCD[0]==128); signal cntCD[1].
//   else : headp3 (wait cntCD[1]==128); atomic logit finish.
// LDS union ~19.5 KB -> 8 blocks/CU -> all 512 co-resident.
// ---------------------------------------------------------------------------
__global__ __launch_bounds__(256) void fh_k(
    const float* __restrict__ A1, const float* __restrict__ Stat,
    const float* __restrict__ g1v, const float* __restrict__ b1v,
    const float* __restrict__ W1, const float* __restrict__ b1,
    const float* __restrict__ W2, const float* __restrict__ b2,
    const float* __restrict__ g2v, const float* __restrict__ b2v,
    const float* __restrict__ Wh, const float* __restrict__ bh,
    const float* __restrict__ Wf, const float* __restrict__ bf,
    float* __restrict__ Hp1, float* __restrict__ Hp2,
    int* __restrict__ cntCD, float* __restrict__ Acc, int* __restrict__ Cnt,
    float* __restrict__ out)
{
    __shared__ float at[32][128];
    __shared__ float mrs[32][2];
    __shared__ float xs[512];
    __shared__ float red[256];
    __shared__ float sd[8];
    __shared__ float mr[2];
    int z = blockIdx.x, t = threadIdx.x;

    if (z < 128) {
        // ---- ffn1: jt = z&31, ks = z>>5 ----
        int jt = z & 31, ks = z >> 5;
        if (t < 32) {
            float s = 0.f, q = 0.f;
#pragma unroll
            for (int p8 = 0; p8 < 8; p8++) {
                s += Stat[(t * 8 + p8) * 2];
                q += Stat[(t * 8 + p8) * 2 + 1];
            }
            float mean = s * (1.0f / 512.0f);
            float var = q * (1.0f / 512.0f) - mean * mean;
            mrs[t][0] = mean;
            mrs[t][1] = rsqrtf(var + 0.001f);
        }
        __syncthreads();
#pragma unroll
        for (int i = 0; i < 4; i++) {
            int idx = t + i * 256;
            int row = idx >> 5, f4 = idx & 31;
            int col = ks * 128 + f4 * 4;
            float4 a4 = *(const float4*)&A1[(long)row * 512 + col];
            float4 g4 = *(const float4*)&g1v[col];
            float4 bb = *(const float4*)&b1v[col];
            float mean = mrs[row][0], rstd = mrs[row][1];
            float4 v;
            v.x = (a4.x - mean) * rstd * g4.x + bb.x;
            v.y = (a4.y - mean) * rstd * g4.y + bb.y;
            v.z = (a4.z - mean) * rstd * g4.z + bb.z;
            v.w = (a4.w - mean) * rstd * g4.w + bb.w;
            ((float4*)at)[idx] = v;
        }
        __syncthreads();
        int j = jt * 64 + (t & 63), rg = t >> 6;
        float acc[8] = {};
        const float* wp = W1 + (long)(ks * 128) * 2048 + j;
#pragma unroll 4
        for (int k = 0; k < 128; k++) {
            float wv = wp[(long)k * 2048];
#pragma unroll
            for (int rr = 0; rr < 8; rr++)
                acc[rr] += at[rg * 8 + rr][k] * wv;
        }
#pragma unroll
        for (int rr = 0; rr < 8; rr++)
            Hp1[((long)(ks * 32 + rg * 8 + rr)) * 2048 + j] = acc[rr];
        __syncthreads();
        if (t == 0) {
            __threadfence();
            atomicAdd(&cntCD[0], 1);
        }
    } else if (z < 256) {
        // ---- ffn2: i = z-128; jt = i&7, ks = i>>3 ----
        int i2 = z - 128, jt = i2 & 7, ks = i2 >> 3;
        if (t == 0) {
            while (atomicAdd(&cntCD[0], 0) < 128) __builtin_amdgcn_s_sleep(8);
            __threadfence();
        }
        __syncthreads();
#pragma unroll
        for (int i = 0; i < 4; i++) {
            int idx = t + i * 256;
            int row = idx >> 5, f4 = idx & 31;
            int col4 = ks * 32 + f4;
            float4 v = ((const float4*)b1)[col4];
#pragma unroll
            for (int p = 0; p < 4; p++) {
                float4 pv = ((const float4*)Hp1)[(long)p * 16384 + (long)row * 512 + col4];
                v.x += pv.x; v.y += pv.y; v.z += pv.z; v.w += pv.w;
            }
            v.x = fmaxf(v.x, 0.f); v.y = fmaxf(v.y, 0.f);
            v.z = fmaxf(v.z, 0.f); v.w = fmaxf(v.w, 0.f);
            ((float4*)at)[idx] = v;
        }
        __syncthreads();
        int j = jt * 64 + (t & 63), rg = t >> 6;
        float acc[8] = {};
        const float* wp = W2 + (long)(ks * 128) * 512 + j;
#pragma unroll 4
        for (int k = 0; k < 128; k++) {
            float wv = wp[(long)k * 512];
#pragma unroll
            for (int rr = 0; rr < 8; rr++)
                acc[rr] += at[rg * 8 + rr][k] * wv;
        }
#pragma unroll
        for (int rr = 0; rr < 8; rr++)
            Hp2[((long)(ks * 32 + rg * 8 + rr)) * 512 + j] = acc[rr];
        __syncthreads();
        if (t == 0) {
            __threadfence();
            atomicAdd(&cntCD[1], 1);
        }
    } else {
        // ---- headp3: i = z-256; b = i>>3, jt = i&7 ----
        int i2 = z - 256, b = i2 >> 3, jt = i2 & 7;
        if (t == 0) {
            while (atomicAdd(&cntCD[1], 0) < 128) __builtin_amdgcn_s_sleep(8);
            __threadfence();
            float s = 0.f, q = 0.f;
#pragma unroll
            for (int p8 = 0; p8 < 8; p8++) {
                s += Stat[(b * 8 + p8) * 2];
                q += Stat[(b * 8 + p8) * 2 + 1];
            }
            float mean = s * (1.0f / 512.0f);
            mr[0] = mean;
            mr[1] = rsqrtf(q * (1.0f / 512.0f) - mean * mean + 0.001f);
        }
        __syncthreads();
        float mean1 = mr[0], rstd1 = mr[1];
        float a[2];
#pragma unroll
        for (int rep = 0; rep < 2; rep++) {
            int j = t + rep * 256;
            float y1 = (A1[b * 512 + j] - mean1) * rstd1 * g1v[j] + b1v[j];
            float v = b2[j] + y1;
#pragma unroll
            for (int ks = 0; ks < 16; ks++)
                v += Hp2[((long)(ks * 32 + b)) * 512 + j];
            a[rep] = v;
        }
        float s = a[0] + a[1];
#pragma unroll
        for (int off = 32; off; off >>= 1) s += __shfl_down(s, off);
        if ((t & 63) == 0) sd[t >> 6] = s;
        __syncthreads();
        float mean = (sd[0] + sd[1] + sd[2] + sd[3]) * (1.0f / 512.0f);
        float d0 = a[0] - mean, d1 = a[1] - mean;
        float v2 = d0 * d0 + d1 * d1;
#pragma unroll
        for (int off = 32; off; off >>= 1) v2 += __shfl_down(v2, off);
        if ((t & 63) == 0) sd[4 + (t >> 6)] = v2;
        __syncthreads();
        float var = (sd[4] + sd[5] + sd[6] + sd[7]) * (1.0f / 512.0f);
        float rstd = rsqrtf(var + 0.001f);
        xs[t] = d0 * rstd * g2v[t] + b2v[t];
        xs[t + 256] = d1 * rstd * g2v[t + 256] + b2v[t + 256];
        __syncthreads();

        int j = jt * 64 + (t & 63), rg = t >> 6;
        const float* w = Wh + j;
        float acc = 0.f;
#pragma unroll 8
        for (int d = rg * 128; d < rg * 128 + 128; d++)
            acc += xs[d] * w[(long)d * 512];
        red[t] = acc;
        __syncthreads();
        if (t < 64) {
            int jj = jt * 64 + t;
            float hid = red[t] + red[t + 64] + red[t + 128] + red[t + 192] + bh[jj];
            hid = fmaxf(hid, 0.f);
            float p = hid * Wf[jj];
#pragma unroll
            for (int off = 32; off; off >>= 1) p += __shfl_down(p, off);
            if (t == 0) {
                atomicAdd(&Acc[b], p);
                __threadfence();
                int old = atomicAdd(&Cnt[b], 1);
                if (old == 7) {
                    float tot = atomicAdd(&Acc[b], 0.0f);
                    float logit = tot + bf[0];
                    out[b] = logit;
                    out[32 + b] = 1.f / (1.f + expf(-logit));
                }
            }
        }
    }
}

// ---------------------------------------------------------------------------
extern "C" void kernel_launch(void* const* d_in, const int* in_sizes, int n_in,
                              void* d_out, int out_size, void* d_ws, size_t ws_size,
                              hipStream_t stream)
{
    const int*   inputs = (const int*)  d_in[0];
    const float* emb    = (const float*)d_in[1];
    const float* Wp     = (const float*)d_in[2];
    const float* bp     = (const float*)d_in[3];
    const float* Wo     = (const float*)d_in[4];
    const float* bo     = (const float*)d_in[5];
    const float* ln1_g  = (const float*)d_in[6];
    const float* ln1_b  = (const float*)d_in[7];
    const float* W1     = (const float*)d_in[8];
    const float* b1     = (const float*)d_in[9];
    const float* W2     = (const float*)d_in[10];
    const float* b2     = (const float*)d_in[11];
    const float* ln2_g  = (const float*)d_in[12];
    const float* ln2_b  = (const float*)d_in[13];
    const float* Wh     = (const float*)d_in[14];
    const float* bh     = (const float*)d_in[15];
    const float* Wf     = (const float*)d_in[16];
    const float* bf     = (const float*)d_in[17];
    float* out = (float*)d_out;

    char* p = (char*)d_ws;
    float* X0    = (float*)p;  p += 65536;      // (32,512)
    float* r     = (float*)p;  p += 262144;     // (128,512)
    float* alpha = (float*)p;  p += 1024;       // (128)+pad
    float* Gp    = (float*)p;  p += 8192;       // (32,16,4)
    float* Tpp   = (float*)p;  p += 4194304;    // (32,16,4,512)
    float* C0    = (float*)p;  p += 65536;      // (32,512)
    float* A1    = (float*)p;  p += 65536;      // (32,512)  pre-LN1
    float* Stat  = (float*)p;  p += 2048;       // (32,8,2)
    int*   zbase = (int*)p;    p += 512;        // 128 dwords: Acc|Cnt|cntA|cntCD
    float* Acc   = (float*)zbase;
    int*   Cnt   = zbase + 32;
    int*   cntA  = zbase + 64;
    int*   cntCD = zbase + 96;
    float* Hp1   = (float*)p;  p += 1048576;    // (4,32,2048)
    float* Hp2   = (float*)p;  p += 1048576;    // (16,32,512)

    qr_k<<<dim3(32, 4), 256, 0, stream>>>(inputs, emb, Wp, bp, X0, r, alpha,
                                          zbase);
    xu_k<<<dim3(32, 16), 256, 0, stream>>>(inputs, emb, r, alpha, Tpp, Gp);
    attf_k<<<dim3(32, 16), 256, 0, stream>>>(Tpp, Gp, Wp, bp, Wo, bo, X0,
                                             C0, A1, Stat, cntA);
    fh_k<<<512, 256, 0, stream>>>(A1, Stat, ln1_g, ln1_b, W1, b1, W2, b2,
                                  ln2_g, ln2_b, Wh, bh, Wf, bf,
                                  Hp1, Hp2, cntCD, Acc, Cnt, out);
}

// Round 14
// 196.044 us; speedup vs baseline: 1.2339x; 1.2339x over previous
//
#include <hip/hip_runtime.h>
#include <hip/hip_bf16.h>

// ---------------------------------------------------------------------------
// qr_k: per (b,h): X0row = emb[tok[b,0]] + PE_row0 (sin0=0 even d, cos0=1 odd)
//   q0[f] = X0row . Wq[h][:,f] + bq[f];  alpha[b,h] = q0 . bk[h]
//   r[(b*4+h)][d] = sum_f q0[f] * Wk[h][d][f]
// Grid (32 b, 4 h).  Block (0,0) also zeroes Acc/Cnt for headp3's atomics.
// ---------------------------------------------------------------------------
__global__ __launch_bounds__(256) void qr_k(
    const int* __restrict__ inp, const float* __restrict__ emb,
    const float* __restrict__ Wp, const float* __restrict__ bp,
    float* __restrict__ X0, float* __restrict__ r, float* __restrict__ alpha,
    float* __restrict__ Acc, int* __restrict__ Cnt)
{
    __shared__ float xs[512];
    __shared__ float red[256];
    __shared__ float q0s[128];
    int b = blockIdx.x, h = blockIdx.y, t = threadIdx.x;
    if (b == 0 && h == 0) {
        if (t < 32) Acc[t] = 0.f;
        else if (t < 64) Cnt[t - 32] = 0;
    }
    int tok0 = inp[b * 1024];
#pragma unroll
    for (int rep = 0; rep < 2; rep++) {
        int d = t + rep * 256;
        float v = emb[(long)tok0 * 512 + d] + ((d & 1) ? 1.0f : 0.0f);
        xs[d] = v;
        if (h == 0) X0[b * 512 + d] = v;
    }
    __syncthreads();

    int f = t & 127, dh = t >> 7;
    const float* wq = Wp + (long)h * 196608 + f;
    float acc = 0.f;
#pragma unroll 8
    for (int d = dh * 256; d < dh * 256 + 256; d++)
        acc += xs[d] * wq[(long)d * 384];
    red[t] = acc;
    __syncthreads();
    if (t < 128) q0s[t] = red[t] + red[t + 128] + bp[h * 384 + t];
    __syncthreads();
    if (t < 128) red[t] = q0s[t] * bp[h * 384 + 128 + t];
    __syncthreads();
    for (int w = 64; w >= 1; w >>= 1) {
        if (t < w) red[t] += red[t + w];
        __syncthreads();
    }
    if (t == 0) alpha[b * 4 + h] = red[0];

    const float4* q4 = (const float4*)q0s;
#pragma unroll
    for (int rep = 0; rep < 2; rep++) {
        int d = t + rep * 256;
        const float4* wr = (const float4*)(Wp + ((long)(h * 512 + d)) * 384 + 128);
        float a2 = 0.f;
#pragma unroll 8
        for (int f4 = 0; f4 < 32; f4++) {
            float4 w = wr[f4], qq = q4[f4];
            a2 += w.x * qq.x + w.y * qq.y + w.z * qq.z + w.w * qq.w;
        }
        r[((long)(b * 4 + h)) * 512 + d] = a2;
    }
}

// ---------------------------------------------------------------------------
// xu_k: fused x-gather (PE via native __sinf/__cosf) -> u -> t' partials.
// Grid (32 b, 16 sg), 2 chunks of 32 s per block.
// rs padded to stride 520 (bank-conflict-free).
// ---------------------------------------------------------------------------
__global__ __launch_bounds__(256) void xu_k(
    const int* __restrict__ inp, const float* __restrict__ emb,
    const float* __restrict__ r, const float* __restrict__ alpha,
    float* __restrict__ Tpp, float* __restrict__ Gp)
{
    __shared__ float xs[32 * 516];     // 66 KB
    __shared__ float rs[4 * 520];      // padded stride
    __shared__ float us[128];          // u[s][h]
    __shared__ int  toks[32];
    int b = blockIdx.x, sg = blockIdx.y, t = threadIdx.x;
    int wave = t >> 6, lane = t & 63;

#pragma unroll
    for (int i = 0; i < 2; i++) {
        int idx = t + i * 256;             // < 512 float4-units
        int h = idx >> 7, k4 = idx & 127;
        *(float4*)&rs[h * 520 + k4 * 4] =
            *(const float4*)&r[((long)(b * 4 + h)) * 512 + k4 * 4];
    }

    float w4[4];
#pragma unroll
    for (int j = 0; j < 4; j++) {
        float expo = (float)(lane * 8 + j * 2) * (1.0f / 512.0f);
        w4[j] = exp2f(-expo * 13.287712379549449f);   // 10000^-expo
    }

    float accT[4][2] = {};
    float gacc = 0.f;
    for (int it = 0; it < 2; it++) {
        int s0 = (sg * 2 + it) * 32;
        __syncthreads();                    // protect xs/us from prev readers
        if (t < 32) toks[t] = inp[b * 1024 + s0 + t];
        __syncthreads();

        // Phase 1: each wave stages 8 rows; x = emb[tok] + PE(s,d) inline
#pragma unroll
        for (int i = 0; i < 8; i++) {
            int row = wave * 8 + i;
            float s = (float)(s0 + row);
            int tok = toks[row];
            const float4* e = (const float4*)&emb[(long)tok * 512 + lane * 8];
            float4 e0 = e[0], e1 = e[1];
            float sv[4], cv[4];
#pragma unroll
            for (int j = 0; j < 4; j++) {
                float ang = s * w4[j];
                sv[j] = __sinf(ang);
                cv[j] = __cosf(ang);
            }
            *(float4*)&xs[row * 516 + lane * 8] =
                make_float4(e0.x + sv[0], e0.y + cv[0], e0.z + sv[1], e0.w + cv[1]);
            *(float4*)&xs[row * 516 + lane * 8 + 4] =
                make_float4(e1.x + sv[2], e1.y + cv[2], e1.z + sv[3], e1.w + cv[3]);
        }
        __syncthreads();

        // Phase 2: u[s,h] = x[s].r[h] + alpha[h]   (thread = (s,h,half))
        {
            int s = t >> 3, h = (t >> 1) & 3, half = t & 1;
            const float* xrow = xs + s * 516 + half * 256;
            const float* rrow = rs + h * 520 + half * 256;
            float acc = 0.f;
#pragma unroll 8
            for (int k = 0; k < 64; k++) {
                float4 xv = *(const float4*)&xrow[k * 4];
                float4 rv = *(const float4*)&rrow[k * 4];
                acc += xv.x * rv.x + xv.y * rv.y + xv.z * rv.z + xv.w * rv.w;
            }
            acc += __shfl_xor(acc, 1);
            if (half == 0) us[s * 4 + h] = acc + alpha[b * 4 + h];
        }
        __syncthreads();

        // gamma partial
        if (t < 4) {
#pragma unroll
            for (int s = 0; s < 32; s++) gacc += us[s * 4 + t];
        }

        // Phase 3: t' partials, d = t and t+256
#pragma unroll 4
        for (int s = 0; s < 32; s++) {
            float x0 = xs[s * 516 + t];
            float x1 = xs[s * 516 + 256 + t];
#pragma unroll
            for (int h = 0; h < 4; h++) {
                float uv = us[s * 4 + h];
                accT[h][0] += uv * x0;
                accT[h][1] += uv * x1;
            }
        }
    }
    long base = (long)(b * 16 + sg) * 2048;
#pragma unroll
    for (int h = 0; h < 4; h++) {
        Tpp[base + h * 512 + t] = accT[h][0];
        Tpp[base + h * 512 + 256 + t] = accT[h][1];
    }
    if (t < 4) Gp[(b * 16 + sg) * 4 + t] = gacc;
}

// ---------------------------------------------------------------------------
// att1_k: c0[b,h*128+e] = scale*(sum_d t'[h][d] Wv[h][d][e] + gamma[h] bv)
// Grid (32 b, 8 jt). Sums 16 sg-partials of t' and gamma on load.
// ---------------------------------------------------------------------------
__global__ __launch_bounds__(256) void att1_k(
    const float* __restrict__ Tpp, const float* __restrict__ Gp,
    const float* __restrict__ Wp, const float* __restrict__ bp,
    float* __restrict__ C0)
{
    __shared__ float tps[512];
    __shared__ float red[256];
    int b = blockIdx.x, jt = blockIdx.y, t = threadIdx.x;
    int h = jt >> 1, e0 = (jt & 1) * 64;
#pragma unroll
    for (int i = 0; i < 2; i++) {
        int d = t + i * 256;
        float v = 0.f;
#pragma unroll 8
        for (int sg = 0; sg < 16; sg++)
            v += Tpp[(long)b * 32768 + sg * 2048 + h * 512 + d];
        tps[d] = v;
    }
    __syncthreads();
    int e = e0 + (t & 63), rg = t >> 6;
    const float* wv = Wp + (long)h * 196608 + 256 + e;
    float acc = 0.f;
#pragma unroll 8
    for (int d = rg * 128; d < rg * 128 + 128; d++)
        acc += tps[d] * wv[(long)d * 384];
    red[t] = acc;
    __syncthreads();
    if (t < 64) {
        float gam = 0.f;
#pragma unroll
        for (int sg = 0; sg < 16; sg++) gam += Gp[(b * 16 + sg) * 4 + h];
        float sum = red[t] + red[t + 64] + red[t + 128] + red[t + 192];
        float c = 0.03125f * (sum + gam * bp[h * 384 + 256 + e0 + t]);
        C0[b * 512 + h * 128 + e0 + t] = c;
    }
}

// ---------------------------------------------------------------------------
// att2s_k: A1 = C0 @ Wo + bo + X0 (pre-LN1 activations) and per-(b,jt)
//   LN stats (sum, sumsq over its 64 cols).  Grid (32 b, 8 jt).
// ---------------------------------------------------------------------------
__global__ __launch_bounds__(256) void att2s_k(
    const float* __restrict__ C0, const float* __restrict__ Wo,
    const float* __restrict__ bo, const float* __restrict__ X0,
    float* __restrict__ A1, float* __restrict__ Stat)
{
    __shared__ float c0s[512];
    __shared__ float red[256];
    int b = blockIdx.x, jt = blockIdx.y, t = threadIdx.x;
    c0s[t] = C0[b * 512 + t];
    c0s[t + 256] = C0[b * 512 + t + 256];
    __syncthreads();
    int j = jt * 64 + (t & 63), rg = t >> 6;
    float acc = 0.f;
#pragma unroll 8
    for (int d = rg * 128; d < rg * 128 + 128; d++)
        acc += c0s[d] * Wo[(long)d * 512 + j];
    red[t] = acc;
    __syncthreads();
    if (t < 64) {
        int jj = jt * 64 + t;
        float a = red[t] + red[t + 64] + red[t + 128] + red[t + 192]
                + bo[jj] + X0[b * 512 + jj];
        A1[b * 512 + jj] = a;
        float s = a, q = a * a;
#pragma unroll
        for (int off = 32; off; off >>= 1) {
            s += __shfl_down(s, off);
            q += __shfl_down(q, off);
        }
        if (t == 0) {
            Stat[(b * 8 + jt) * 2]     = s;
            Stat[(b * 8 + jt) * 2 + 1] = q;
        }
    }
}

// ---------------------------------------------------------------------------
// ffn1_k: LN1-on-load + Hp1[ks][32][2048] = Y1[:, kchunk] @ W1[kchunk, :]
// Grid (32 jt, 4 ks). Y1 = (A1 - mean)*rstd*g1 + b1v from Stat partials.
// ---------------------------------------------------------------------------
__global__ __launch_bounds__(256) void ffn1_k(
    const float* __restrict__ A1, const float* __restrict__ Stat,
    const float* __restrict__ g1, const float* __restrict__ b1v,
    const float* __restrict__ W1, float* __restrict__ Hp1)
{
    __shared__ float at[32][128];
    __shared__ float mrs[32][2];
    int jt = blockIdx.x, ks = blockIdx.y, t = threadIdx.x;
    if (t < 32) {
        float s = 0.f, q = 0.f;
#pragma unroll
        for (int p8 = 0; p8 < 8; p8++) {
            s += Stat[(t * 8 + p8) * 2];
            q += Stat[(t * 8 + p8) * 2 + 1];
        }
        float mean = s * (1.0f / 512.0f);
        float var = q * (1.0f / 512.0f) - mean * mean;
        mrs[t][0] = mean;
        mrs[t][1] = rsqrtf(var + 0.001f);
    }
    __syncthreads();
#pragma unroll
    for (int i = 0; i < 4; i++) {
        int idx = t + i * 256;
        int row = idx >> 5, f4 = idx & 31;
        int col = ks * 128 + f4 * 4;
        float4 a4 = *(const float4*)&A1[(long)row * 512 + col];
        float4 g4 = *(const float4*)&g1[col];
        float4 bb = *(const float4*)&b1v[col];
        float mean = mrs[row][0], rstd = mrs[row][1];
        float4 v;
        v.x = (a4.x - mean) * rstd * g4.x + bb.x;
        v.y = (a4.y - mean) * rstd * g4.y + bb.y;
        v.z = (a4.z - mean) * rstd * g4.z + bb.z;
        v.w = (a4.w - mean) * rstd * g4.w + bb.w;
        ((float4*)at)[idx] = v;
    }
    __syncthreads();
    int j = jt * 64 + (t & 63), rg = t >> 6;
    float acc[8] = {};
    const float* wp = W1 + (long)(ks * 128) * 2048 + j;
#pragma unroll 4
    for (int k = 0; k < 128; k++) {
        float wv = wp[(long)k * 2048];
#pragma unroll
        for (int rr = 0; rr < 8; rr++)
            acc[rr] += at[rg * 8 + rr][k] * wv;
    }
#pragma unroll
    for (int rr = 0; rr < 8; rr++)
        Hp1[((long)(ks * 32 + rg * 8 + rr)) * 2048 + j] = acc[rr];
}

// ---------------------------------------------------------------------------
// FFN2 partials, fused H1 = relu(sum_ks Hp1 + b1) at staging.
// Grid (8 jt, 16 ks).
// ---------------------------------------------------------------------------
__global__ __launch_bounds__(256) void ffn2_k(
    const float* __restrict__ Hp1, const float* __restrict__ b1,
    const float* __restrict__ W2, float* __restrict__ Hp2)
{
    __shared__ float at[32][128];
    int jt = blockIdx.x, ks = blockIdx.y, t = threadIdx.x;
#pragma unroll
    for (int i = 0; i < 4; i++) {
        int idx = t + i * 256;
        int row = idx >> 5, f4 = idx & 31;
        int col4 = ks * 32 + f4;
        float4 v = ((const float4*)b1)[col4];
#pragma unroll
        for (int p = 0; p < 4; p++) {
            float4 pv = ((const float4*)Hp1)[(long)p * 16384 + (long)row * 512 + col4];
            v.x += pv.x; v.y += pv.y; v.z += pv.z; v.w += pv.w;
        }
        v.x = fmaxf(v.x, 0.f); v.y = fmaxf(v.y, 0.f);
        v.z = fmaxf(v.z, 0.f); v.w = fmaxf(v.w, 0.f);
        ((float4*)at)[idx] = v;
    }
    __syncthreads();
    int j = jt * 64 + (t & 63), rg = t >> 6;
    float acc[8] = {};
    const float* wp = W2 + (long)(ks * 128) * 512 + j;
#pragma unroll 4
    for (int k = 0; k < 128; k++) {
        float wv = wp[(long)k * 512];
#pragma unroll
        for (int rr = 0; rr < 8; rr++)
            acc[rr] += at[rg * 8 + rr][k] * wv;
    }
#pragma unroll
    for (int rr = 0; rr < 8; rr++)
        Hp2[((long)(ks * 32 + rg * 8 + rr)) * 512 + j] = acc[rr];
}

// ---------------------------------------------------------------------------
// headp3_k: Y1 recompute (LN1 from A1+Stat) + LN2 + head partial + atomic
//   finish (8th arriver per b computes logit+sigmoid, writes out).
// Grid (32 b, 8 jt).
// ---------------------------------------------------------------------------
__global__ __launch_bounds__(256) void headp3_k(
    const float* __restrict__ Hp2, const float* __restrict__ b2,
    const float* __restrict__ A1, const float* __restrict__ Stat,
    const float* __restrict__ g1v, const float* __restrict__ b1v,
    const float* __restrict__ g2v, const float* __restrict__ b2v,
    const float* __restrict__ Wh, const float* __restrict__ bh,
    const float* __restrict__ Wf, const float* __restrict__ bf,
    float* __restrict__ Acc, int* __restrict__ Cnt, float* __restrict__ out)
{
    __shared__ float xs[512];
    __shared__ float red[256];
    __shared__ float sd[8];
    __shared__ float mr[2];
    int b = blockIdx.x, jt = blockIdx.y, t = threadIdx.x;
    if (t == 0) {
        float s = 0.f, q = 0.f;
#pragma unroll
        for (int p8 = 0; p8 < 8; p8++) {
            s += Stat[(b * 8 + p8) * 2];
            q += Stat[(b * 8 + p8) * 2 + 1];
        }
        float mean = s * (1.0f / 512.0f);
        mr[0] = mean;
        mr[1] = rsqrtf(q * (1.0f / 512.0f) - mean * mean + 0.001f);
    }
    __syncthreads();
    float mean1 = mr[0], rstd1 = mr[1];
    float a[2];
#pragma unroll
    for (int rep = 0; rep < 2; rep++) {
        int j = t + rep * 256;
        float y1 = (A1[b * 512 + j] - mean1) * rstd1 * g1v[j] + b1v[j];
        float v = b2[j] + y1;
#pragma unroll
        for (int ks = 0; ks < 16; ks++)
            v += Hp2[((long)(ks * 32 + b)) * 512 + j];
        a[rep] = v;
    }
    float s = a[0] + a[1];
#pragma unroll
    for (int off = 32; off; off >>= 1) s += __shfl_down(s, off);
    if ((t & 63) == 0) sd[t >> 6] = s;
    __syncthreads();
    float mean = (sd[0] + sd[1] + sd[2] + sd[3]) * (1.0f / 512.0f);
    float d0 = a[0] - mean, d1 = a[1] - mean;
    float v2 = d0 * d0 + d1 * d1;
#pragma unroll
    for (int off = 32; off; off >>= 1) v2 += __shfl_down(v2, off);
    if ((t & 63) == 0) sd[4 + (t >> 6)] = v2;
    __syncthreads();
    float var = (sd[4] + sd[5] + sd[6] + sd[7]) * (1.0f / 512.0f);
    float rstd = rsqrtf(var + 0.001f);
    xs[t] = d0 * rstd * g2v[t] + b2v[t];
    xs[t + 256] = d1 * rstd * g2v[t + 256] + b2v[t + 256];
    __syncthreads();

    int j = jt * 64 + (t & 63), rg = t >> 6;
    const float* w = Wh + j;
    float acc = 0.f;
#pragma unroll 8
    for (int d = rg * 128; d < rg * 128 + 128; d++)
        acc += xs[d] * w[(long)d * 512];
    red[t] = acc;
    __syncthreads();
    if (t < 64) {
        int jj = jt * 64 + t;
        float hid = red[t] + red[t + 64] + red[t + 128] + red[t + 192] + bh[jj];
        hid = fmaxf(hid, 0.f);
        float p = hid * Wf[jj];
#pragma unroll
        for (int off = 32; off; off >>= 1) p += __shfl_down(p, off);
        if (t == 0) {
            atomicAdd(&Acc[b], p);
            __threadfence();
            int old = atomicAdd(&Cnt[b], 1);
            if (old == 7) {
                float tot = atomicAdd(&Acc[b], 0.0f);
                float logit = tot + bf[0];
                out[b] = logit;
                out[32 + b] = 1.f / (1.f + expf(-logit));
            }
        }
    }
}

// ---------------------------------------------------------------------------
extern "C" void kernel_launch(void* const* d_in, const int* in_sizes, int n_in,
                              void* d_out, int out_size, void* d_ws, size_t ws_size,
                              hipStream_t stream)
{
    const int*   inputs = (const int*)  d_in[0];
    const float* emb    = (const float*)d_in[1];
    const float* Wp     = (const float*)d_in[2];
    const float* bp     = (const float*)d_in[3];
    const float* Wo     = (const float*)d_in[4];
    const float* bo     = (const float*)d_in[5];
    const float* ln1_g  = (const float*)d_in[6];
    const float* ln1_b  = (const float*)d_in[7];
    const float* W1     = (const float*)d_in[8];
    const float* b1     = (const float*)d_in[9];
    const float* W2     = (const float*)d_in[10];
    const float* b2     = (const float*)d_in[11];
    const float* ln2_g  = (const float*)d_in[12];
    const float* ln2_b  = (const float*)d_in[13];
    const float* Wh     = (const float*)d_in[14];
    const float* bh     = (const float*)d_in[15];
    const float* Wf     = (const float*)d_in[16];
    const float* bf     = (const float*)d_in[17];
    float* out = (float*)d_out;

    char* p = (char*)d_ws;
    float* X0    = (float*)p;  p += 65536;      // (32,512)
    float* r     = (float*)p;  p += 262144;     // (128,512)
    float* alpha = (float*)p;  p += 1024;       // (128)+pad
    float* Gp    = (float*)p;  p += 8192;       // (32,16,4)
    float* Tpp   = (float*)p;  p += 4194304;    // (32,16,4,512)
    float* C0    = (float*)p;  p += 65536;      // (32,512)
    float* A1    = (float*)p;  p += 65536;      // (32,512)  pre-LN1
    float* Stat  = (float*)p;  p += 2048;       // (32,8,2)
    float* Acc   = (float*)p;  p += 512;        // (32)+pad
    int*   Cnt   = (int*)p;    p += 512;        // (32)+pad
    float* Hp1   = (float*)p;  p += 1048576;    // (4,32,2048)
    float* Hp2   = (float*)p;  p += 1048576;    // (16,32,512)

    qr_k<<<dim3(32, 4), 256, 0, stream>>>(inputs, emb, Wp, bp, X0, r, alpha,
                                          Acc, Cnt);
    xu_k<<<dim3(32, 16), 256, 0, stream>>>(inputs, emb, r, alpha, Tpp, Gp);
    att1_k<<<dim3(32, 8), 256, 0, stream>>>(Tpp, Gp, Wp, bp, C0);
    att2s_k<<<dim3(32, 8), 256, 0, stream>>>(C0, Wo, bo, X0, A1, Stat);
    ffn1_k<<<dim3(32, 4), 256, 0, stream>>>(A1, Stat, ln1_g, ln1_b, W1, Hp1);
    ffn2_k<<<dim3(8, 16), 256, 0, stream>>>(Hp1, b1, W2, Hp2);
    headp3_k<<<dim3(32, 8), 256, 0, stream>>>(Hp2, b2, A1, Stat,
                                              ln1_g, ln1_b, ln2_g, ln2_b,
                                              Wh, bh, Wf, bf, Acc, Cnt, out);
}